// Round 8
// baseline (4226.496 us; speedup 1.0000x reference)
//
#include <hip/hip_runtime.h>
#include <cstdint>
#include <cstddef>

// Problem constants
#define N_TOK   16384      // 16*32*32 tokens
#define K_CODE  8192
#define D_DIM   256
#define HW      1024       // 32*32
#define MARGIN  8e-4f      // >= 2*bf16 err bound + dist-grid/tie slack, 2x safety (R2-proven)
#define RING    64

// d_out layout (floats): z_q, commit, codebook, usage, new_cluster, new_embed_avg
#define OFF_ZQ   0
#define OFF_CL   4194304
#define OFF_CBL  4194305
#define OFF_USE  4194306
#define OFF_NC   4202498
#define OFF_AVG  4210690

typedef unsigned short ushort_t;
typedef __attribute__((ext_vector_type(8))) short short8;
typedef __attribute__((ext_vector_type(8))) unsigned short ushort8;
typedef __attribute__((ext_vector_type(4))) float f32x4;

// Device-global scratch
__device__ float g_esq[K_CODE];
__device__ float g_xsq[N_TOK];
__device__ __attribute__((aligned(16))) float    g_xf[N_TOK * D_DIM];   // flat fp32 [n][d]
__device__ __attribute__((aligned(16))) ushort_t g_xb[N_TOK * D_DIM];   // bf16, row-swizzled
__device__ __attribute__((aligned(16))) ushort_t g_wb[K_CODE * D_DIM];  // bf16, row-swizzled
__device__ int   g_ccnt[N_TOK];
__device__ int   g_cand[N_TOK * RING];
__device__ int   g_idx[N_TOK];
__device__ float g_cnt[K_CODE];
__device__ __attribute__((aligned(16))) float g_esum[K_CODE * D_DIM];
__device__ float g_inv[K_CODE];
__device__ float g_loss[1];

__device__ __forceinline__ ushort_t f2bf(float f) {
  unsigned u = __builtin_bit_cast(unsigned, f);
  return (ushort_t)((u + 0x7FFFu + ((u >> 16) & 1u)) >> 16);   // RNE, no NaN in data
}

__device__ __forceinline__ void gload16(const void* g, void* l) {
  __builtin_amdgcn_global_load_lds(
      (const __attribute__((address_space(1))) unsigned int*)g,
      (__attribute__((address_space(3))) unsigned int*)l, 16, 0, 0);
}

// ---------------- zero scratch ----------------
__global__ void k_zero() {
  int i = blockIdx.x * 256 + threadIdx.x;          // 524288 threads
  if (i < K_CODE) g_cnt[i] = 0.0f;
  if (i < N_TOK) g_ccnt[i] = 0;
  if (i == 0) g_loss[0] = 0.0f;
  for (int j = i; j < K_CODE * D_DIM; j += 524288) g_esum[j] = 0.0f;
}

// ---------------- e_sq[k] = sum_d w[k][d]^2 (absorbed by ref rounding; order-free) ----------------
__global__ void k_esq(const float* __restrict__ wt) {
  int t = threadIdx.x;
  int code = blockIdx.x * 4 + (t >> 6);
  int l = t & 63;
  float4 v = *(const float4*)(wt + (size_t)code * D_DIM + l * 4);
  float s = v.x * v.x + v.y * v.y + v.z * v.z + v.w * v.w;
  #pragma unroll
  for (int m = 1; m < 64; m <<= 1) s += __shfl_xor(s, m, 64);
  if (l == 0) g_esq[code] = s;
}

// ---------------- codebook -> bf16, 16B-granule XOR swizzle per row ----------------
__global__ void k_split_w(const float* __restrict__ wt) {
  int tg = blockIdx.x * 256 + threadIdx.x;         // 262144 = 8192 codes * 32 granules
  int c = tg >> 5, g = tg & 31;
  const float* src = wt + (size_t)c * D_DIM + g * 8;
  float4 v0 = *(const float4*)(src);
  float4 v1 = *(const float4*)(src + 4);
  ushort8 v;
  v[0] = f2bf(v0.x); v[1] = f2bf(v0.y); v[2] = f2bf(v0.z); v[3] = f2bf(v0.w);
  v[4] = f2bf(v1.x); v[5] = f2bf(v1.y); v[6] = f2bf(v1.z); v[7] = f2bf(v1.w);
  *(ushort8*)(g_wb + (size_t)c * D_DIM + ((g ^ (c & 7)) << 3)) = v;
}

// ---------------- z_e -> flat fp32 rows + x_sq (sequential, contract-off) + bf16 swizzled ----------------
__global__ __launch_bounds__(256) void k_prep_x(const float* __restrict__ ze) {
  extern __shared__ char smem[];
  float* T = (float*)smem;                          // [64][260]
  const int tid = threadIdx.x;
  const int n0 = blockIdx.x * 64;
  const int b = n0 >> 10, hw0 = n0 & 1023;
  const float* zb = ze + (size_t)b * (D_DIM * HW) + hw0;
  #pragma unroll
  for (int p = 0; p < 16; ++p) {
    int idx = p * 256 + tid;
    int d = idx >> 4, f = idx & 15;
    float4 v = *(const float4*)(zb + (size_t)d * HW + f * 4);
    T[(f * 4 + 0) * 260 + d] = v.x;
    T[(f * 4 + 1) * 260 + d] = v.y;
    T[(f * 4 + 2) * 260 + d] = v.z;
    T[(f * 4 + 3) * 260 + d] = v.w;
  }
  __syncthreads();
  if (tid < 64) {   // x_sq: SEQUENTIAL scalar chain, square rounded before add (matches ref)
    #pragma clang fp contract(off)
    float s = 0.0f;
    const float* tr = T + tid * 260;
    for (int d = 0; d < D_DIM; ++d) { float v = tr[d]; s = s + v * v; }
    g_xsq[n0 + tid] = s;
  }
  {   // fp32 flat rows (row base 1040B = 16B-aligned)
    int r = tid >> 2, dc = (tid & 3) * 64;
    const float* tr = T + r * 260 + dc;
    float* dst = g_xf + (size_t)(n0 + r) * D_DIM + dc;
    #pragma unroll
    for (int j = 0; j < 16; ++j) *(float4*)(dst + j * 4) = *(const float4*)(tr + j * 4);
  }
  {   // bf16 rows, granule g stored at g ^ (row&7)  (row&7 == (n0+r)&7 since 64|n0)
    int r = tid >> 2, gb = (tid & 3) * 8;
    const float* tr = T + r * 260;
    ushort_t* dst = g_xb + (size_t)(n0 + r) * D_DIM;
    int swz = r & 7;
    #pragma unroll
    for (int gg = 0; gg < 8; ++gg) {
      int g = gb + gg;
      ushort8 v;
      #pragma unroll
      for (int j = 0; j < 8; ++j) v[j] = f2bf(tr[g * 8 + j]);
      *(ushort8*)(dst + ((g ^ swz) << 3)) = v;
    }
  }
}

// ---------------- bf16 MFMA GEMM, SINGLE pass: running-max + margin candidate collect ----------------
// Grid 256 = 128 row-blocks x 2 code-halves. 256 thr = 4 waves; wave w owns rows [32w,32w+32).
// LDS 128KB: A [128][256] bf16 resident + B [2][64][256] double-buffered; rows XOR-swizzled.
// Structure identical to R2's k_approx (HW-proven); only the epilogue differs.
__global__ __launch_bounds__(256, 1) void k_approx1() {
  extern __shared__ char smem[];
  ushort_t* As = (ushort_t*)smem;                   // 64KB
  ushort_t* Bs = (ushort_t*)(smem + 65536);         // 2 x 32KB

  const int tid = threadIdx.x;
  const int lane = tid & 63, wid = tid >> 6;
  const int col = lane & 15, kg = lane >> 4;
  const int rb = blockIdx.x & 127, sp = blockIdx.x >> 7;

  {  // stage A once (linear copy of pre-swizzled rows)
    const char* s = (const char*)g_xb + (size_t)rb * 65536 + wid * 16384 + lane * 16;
    char* d = smem + wid * 16384;                   // wave-uniform base; +lane*16 implicit
    #pragma unroll
    for (int it = 0; it < 16; ++it) gload16(s + it * 1024, d + it * 1024);
  }
  const char* wsrc = (const char*)g_wb + (size_t)sp * (4096 * 512);
  {  // stage B chunk 0 -> buf 0
    const char* s = wsrc + wid * 8192 + lane * 16;
    char* d = smem + 65536 + wid * 8192;
    #pragma unroll
    for (int it = 0; it < 8; ++it) gload16(s + it * 1024, d + it * 1024);
  }

  const int rbase = rb * 128 + wid * 32;
  float rm[2][4], thr[2][4];
  #pragma unroll
  for (int m = 0; m < 2; ++m)
    #pragma unroll
    for (int r = 0; r < 4; ++r) { rm[m][r] = -1e30f; thr[m][r] = 1e30f; }

  __syncthreads();   // compiler drains vmcnt before s_barrier -> A and B0 resident

  int cur = 0;
  const int ar0 = wid * 32 + col;
  const int sw = col & 7;
  for (int ch = 0; ch < 64; ++ch) {
    if (ch < 63) {   // prefetch next chunk into other buffer
      const char* s = wsrc + (size_t)(ch + 1) * 32768 + wid * 8192 + lane * 16;
      char* d = smem + 65536 + ((cur ^ 1) << 15) + wid * 8192;
      #pragma unroll
      for (int it = 0; it < 8; ++it) gload16(s + it * 1024, d + it * 1024);
    }
    const ushort_t* Bb = Bs + (cur << 14);
    f32x4 acc[2][4];
    const f32x4 zero4 = {0.f, 0.f, 0.f, 0.f};
    #pragma unroll
    for (int m = 0; m < 2; ++m)
      #pragma unroll
      for (int n = 0; n < 4; ++n) acc[m][n] = zero4;

    #pragma unroll
    for (int ks = 0; ks < 8; ++ks) {
      const int kgr = ks * 4 + kg;
      const int ko = (kgr ^ sw) << 3;               // swizzled granule offset (8 bf16)
      short8 a0 = *(const short8*)(As + ar0 * 256 + ko);
      short8 a1 = *(const short8*)(As + (ar0 + 16) * 256 + ko);
      short8 bfr[4];
      #pragma unroll
      for (int n = 0; n < 4; ++n)
        bfr[n] = *(const short8*)(Bb + (n * 16 + col) * 256 + ko);
      #pragma unroll
      for (int n = 0; n < 4; ++n) {
        acc[0][n] = __builtin_amdgcn_mfma_f32_16x16x32_bf16(a0, bfr[n], acc[0][n], 0, 0, 0);
        acc[1][n] = __builtin_amdgcn_mfma_f32_16x16x32_bf16(a1, bfr[n], acc[1][n], 0, 0, 0);
      }
    }
    // ---- single-pass epilogue: score = 2*cross - esq; running-max + margin collect ----
    // D-frag: row = kg*4+r (+16m), col = lane&15 (R2 HW-verified mapping).
    const int c0 = sp * 4096 + ch * 64;
    float cm[2][4];
    #pragma unroll
    for (int m = 0; m < 2; ++m)
      #pragma unroll
      for (int r = 0; r < 4; ++r) cm[m][r] = -1e30f;
    #pragma unroll
    for (int n = 0; n < 4; ++n) {
      const int c = c0 + n * 16 + col;
      const float e = g_esq[c];
      #pragma unroll
      for (int m = 0; m < 2; ++m)
        #pragma unroll
        for (int r = 0; r < 4; ++r) {
          float sc = fmaf(2.0f, acc[m][n][r], -e);
          cm[m][r] = fmaxf(cm[m][r], sc);
          if (ch > 0 && sc >= thr[m][r]) {   // thr only grows -> superset of exact margin set
            int row = rbase + m * 16 + (kg << 2) + r;
            int pos = atomicAdd(&g_ccnt[row], 1);
            if (pos < RING) g_cand[row * RING + pos] = c;
          }
        }
    }
    #pragma unroll
    for (int mk = 1; mk < 16; mk <<= 1)
      #pragma unroll
      for (int m = 0; m < 2; ++m)
        #pragma unroll
        for (int r = 0; r < 4; ++r)
          cm[m][r] = fmaxf(cm[m][r], __shfl_xor(cm[m][r], mk, 64));
    #pragma unroll
    for (int m = 0; m < 2; ++m)
      #pragma unroll
      for (int r = 0; r < 4; ++r) {
        rm[m][r] = fmaxf(rm[m][r], cm[m][r]);
        thr[m][r] = rm[m][r] - MARGIN;
      }
    if (ch == 0) {   // seed chunk: push-sweep now that thr is known
      #pragma unroll
      for (int n = 0; n < 4; ++n) {
        const int c = c0 + n * 16 + col;
        const float e = g_esq[c];
        #pragma unroll
        for (int m = 0; m < 2; ++m)
          #pragma unroll
          for (int r = 0; r < 4; ++r) {
            float sc = fmaf(2.0f, acc[m][n][r], -e);
            if (sc >= thr[m][r]) {
              int row = rbase + m * 16 + (kg << 2) + r;
              int pos = atomicAdd(&g_ccnt[row], 1);
              if (pos < RING) g_cand[row * RING + pos] = c;
            }
          }
      }
    }
    __syncthreads();
    cur ^= 1;
  }
}

// ---------------- exact fp32 rescore of candidates (wave per row) ----------------
__global__ __launch_bounds__(256) void k_rescore(const float* __restrict__ wt) {
  const int lane = threadIdx.x & 63, wid = threadIdx.x >> 6;
  const int n = blockIdx.x * 4 + wid;
  const float4 x = *(const float4*)(g_xf + (size_t)n * D_DIM + lane * 4);
  const float xsq = g_xsq[n];
  const int cnt = g_ccnt[n];
  float bd = INFINITY;
  int bi = 0x7fffffff;
  auto evalc = [&](int c) {
    const float4 w = *(const float4*)(wt + (size_t)c * D_DIM + lane * 4);
    float p = x.x * w.x + x.y * w.y + x.z * w.z + x.w * w.w;
    #pragma unroll
    for (int m = 1; m < 64; m <<= 1) p += __shfl_xor(p, m, 64);
    float d = (xsq + g_esq[c]) - 2.0f * p;   // 2p exact; rounding grid matches reference
    if (d < bd || (d == bd && c < bi)) { bd = d; bi = c; }
  };
  if (cnt >= 1 && cnt <= RING) {
    for (int i = 0; i < cnt; ++i) evalc(g_cand[n * RING + i]);
  } else {                                   // overflow/empty fallback: exact full scan
    for (int c = 0; c < K_CODE; ++c) evalc(c);
  }
  if (lane == 0) g_idx[n] = bi;
}

// ---------------- scatter: counts + embed_sum ----------------
__global__ void k_scatter(const float* __restrict__ ze) {
  __shared__ int codes[64];
  int t = threadIdx.x;
  int n0 = blockIdx.x * 64;
  int b = n0 >> 10, hw0 = n0 & 1023;
  if (t < 64) {
    int c = g_idx[n0 + t];
    codes[t] = c;
    atomicAdd(&g_cnt[c], 1.0f);
  }
  __syncthreads();
  int f = t & 15, dd = t >> 4;
  const float* zb = ze + (size_t)b * (D_DIM * HW) + hw0;
  for (int p = 0; p < 16; ++p) {
    int d = p * 16 + dd;
    float4 v = *(const float4*)(zb + (size_t)d * HW + f * 4);
    atomicAdd(&g_esum[codes[4 * f + 0] * D_DIM + d], v.x);
    atomicAdd(&g_esum[codes[4 * f + 1] * D_DIM + d], v.y);
    atomicAdd(&g_esum[codes[4 * f + 2] * D_DIM + d], v.z);
    atomicAdd(&g_esum[codes[4 * f + 3] * D_DIM + d], v.w);
  }
}

// ---------------- EMA cluster, n, usage, inv_cs ----------------
__global__ void k_ema(const float* __restrict__ cs_in, float* __restrict__ out) {
  __shared__ float red[4];
  int t = threadIdx.x;
  float local = 0.0f;
  for (int k = t; k < K_CODE; k += 256) local += cs_in[k] * 0.99f + g_cnt[k] * 0.01f;
  #pragma unroll
  for (int m = 1; m < 64; m <<= 1) local += __shfl_xor(local, m, 64);
  if ((t & 63) == 0) red[t >> 6] = local;
  __syncthreads();
  float n = red[0] + red[1] + red[2] + red[3];
  float denom = n + 0.08192f;   // n + K*EPS
  for (int k = t; k < K_CODE; k += 256) {
    float newc = cs_in[k] * 0.99f + g_cnt[k] * 0.01f;
    out[OFF_NC + k]  = newc;
    out[OFF_USE + k] = g_cnt[k] * (1.0f / 16384.0f);
    float cs = ((newc + 1e-5f) / denom) * n;
    g_inv[k] = 1.0f / cs;
  }
}

// ---------------- new_embed_avg ----------------
__global__ void k_avg(const float* __restrict__ ea, float* __restrict__ out) {
  int i = blockIdx.x * 256 + threadIdx.x;          // 1048576 float2's
  const float2 a = *(const float2*)(ea + (size_t)i * 2);
  const float2 s = *(const float2*)(g_esum + (size_t)i * 2);
  float2 o;
  o.x = a.x * 0.99f + s.x * 0.01f;
  o.y = a.y * 0.99f + s.y * 0.01f;
  *(float2*)(out + OFF_AVG + (size_t)i * 2) = o;
}

// ---------------- gather z_q + loss ----------------
__global__ __launch_bounds__(256) void k_gather(const float* __restrict__ ze,
                                                float* __restrict__ out) {
  __shared__ float W[32 * 260];
  __shared__ int codes[64];
  __shared__ float red[4];
  const float* avg = out + OFF_AVG;
  int t = threadIdx.x;
  int n0 = blockIdx.x * 64;
  int b = n0 >> 10, hw0 = n0 & 1023;
  if (t < 64) codes[t] = g_idx[n0 + t];
  float l = 0.0f;
  const float* zb = ze + (size_t)b * (D_DIM * HW);
  float* qb = out + OFF_ZQ + (size_t)b * (D_DIM * HW);
  for (int pass = 0; pass < 2; ++pass) {
    __syncthreads();
    {
      int rr0 = t >> 6;
      int f = t & 63;
      for (int q = 0; q < 8; ++q) {
        int rr = q * 4 + rr0;
        int c = codes[pass * 32 + rr];
        float iv = g_inv[c];
        float2 w0 = *(const float2*)(avg + (size_t)c * D_DIM + f * 4);
        float2 w1 = *(const float2*)(avg + (size_t)c * D_DIM + f * 4 + 2);
        float* wp = &W[rr * 260 + f * 4];
        wp[0] = w0.x * iv; wp[1] = w0.y * iv; wp[2] = w1.x * iv; wp[3] = w1.y * iv;
      }
    }
    __syncthreads();
    int f = t & 7, dd = t >> 3;
    int hwp = hw0 + pass * 32;
    for (int p = 0; p < 8; ++p) {
      int d = p * 32 + dd;
      float4 zev = *(const float4*)(zb + (size_t)d * HW + hwp + f * 4);
      float4 o;
      o.x = W[(4 * f + 0) * 260 + d];
      o.y = W[(4 * f + 1) * 260 + d];
      o.z = W[(4 * f + 2) * 260 + d];
      o.w = W[(4 * f + 3) * 260 + d];
      *(float4*)(qb + (size_t)d * HW + hwp + f * 4) = o;
      float dx = zev.x - o.x, dy = zev.y - o.y, dz = zev.z - o.z, dw = zev.w - o.w;
      l += dx * dx; l += dy * dy; l += dz * dz; l += dw * dw;
    }
  }
  #pragma unroll
  for (int m = 1; m < 64; m <<= 1) l += __shfl_xor(l, m, 64);
  if ((t & 63) == 0) red[t >> 6] = l;
  __syncthreads();
  if (t == 0) atomicAdd(g_loss, red[0] + red[1] + red[2] + red[3]);
}

// ---------------- final scalars ----------------
__global__ void k_final(float* __restrict__ out) {
  if (threadIdx.x == 0) {
    float mse = g_loss[0] * (1.0f / 4194304.0f);
    out[OFF_CL]  = 0.25f * mse;
    out[OFF_CBL] = mse;
  }
}

extern "C" void kernel_launch(void* const* d_in, const int* in_sizes, int n_in,
                              void* d_out, int out_size, void* d_ws, size_t ws_size,
                              hipStream_t stream) {
  const float* ze    = (const float*)d_in[0];
  const float* wt    = (const float*)d_in[1];
  const float* cs_in = (const float*)d_in[2];
  const float* ea_in = (const float*)d_in[3];
  float* out = (float*)d_out;
  (void)in_sizes; (void)n_in; (void)out_size; (void)d_ws; (void)ws_size;

  // Dynamic-LDS opt-ins (idempotent; not stream ops)
  (void)hipFuncSetAttribute((const void*)k_prep_x,
                            hipFuncAttributeMaxDynamicSharedMemorySize, 66560);
  (void)hipFuncSetAttribute((const void*)k_approx1,
                            hipFuncAttributeMaxDynamicSharedMemorySize, 131072);

  k_zero<<<2048, 256, 0, stream>>>();
  k_esq<<<K_CODE / 4, 256, 0, stream>>>(wt);
  k_split_w<<<1024, 256, 0, stream>>>(wt);
  k_prep_x<<<N_TOK / 64, 256, 66560, stream>>>(ze);
  k_approx1<<<256, 256, 131072, stream>>>();
  k_rescore<<<N_TOK / 4, 256, 0, stream>>>(wt);
  k_scatter<<<N_TOK / 64, 256, 0, stream>>>(ze);
  k_ema<<<1, 256, 0, stream>>>(cs_in, out);
  k_avg<<<4096, 256, 0, stream>>>(ea_in, out);
  k_gather<<<N_TOK / 64, 256, 0, stream>>>(ze, out);
  k_final<<<1, 64, 0, stream>>>(out);
}

// Round 9
// 633.210 us; speedup vs baseline: 6.6747x; 6.6747x over previous
//
#include <hip/hip_runtime.h>
#include <cstdint>
#include <cstddef>

// Problem constants
#define N_TOK   16384      // 16*32*32 tokens
#define K_CODE  8192
#define D_DIM   256
#define HW      1024       // 32*32
#define MARGIN  8e-4f      // >= 2*bf16 err bound + dist-grid/tie slack, 2x safety (R2-proven)
#define RING    512        // R8: mean pushes ~34/row, RING=64 overflowed ~0.1-1% rows -> ms full scans

// d_out layout (floats): z_q, commit, codebook, usage, new_cluster, new_embed_avg
#define OFF_ZQ   0
#define OFF_CL   4194304
#define OFF_CBL  4194305
#define OFF_USE  4194306
#define OFF_NC   4202498
#define OFF_AVG  4210690

typedef unsigned short ushort_t;
typedef __attribute__((ext_vector_type(8))) short short8;
typedef __attribute__((ext_vector_type(8))) unsigned short ushort8;
typedef __attribute__((ext_vector_type(4))) float f32x4;

// Device-global scratch
__device__ float g_esq[K_CODE];
__device__ float g_xsq[N_TOK];
__device__ __attribute__((aligned(16))) float    g_xf[N_TOK * D_DIM];   // flat fp32 [n][d]
__device__ __attribute__((aligned(16))) ushort_t g_xb[N_TOK * D_DIM];   // bf16, row-swizzled
__device__ __attribute__((aligned(16))) ushort_t g_wb[K_CODE * D_DIM];  // bf16, row-swizzled
__device__ int   g_ccnt[N_TOK];
__device__ int   g_cand[N_TOK * RING];
__device__ int   g_idx[N_TOK];
__device__ float g_cnt[K_CODE];
__device__ __attribute__((aligned(16))) float g_esum[K_CODE * D_DIM];
__device__ float g_inv[K_CODE];
__device__ float g_loss[1];

__device__ __forceinline__ ushort_t f2bf(float f) {
  unsigned u = __builtin_bit_cast(unsigned, f);
  return (ushort_t)((u + 0x7FFFu + ((u >> 16) & 1u)) >> 16);   // RNE, no NaN in data
}

__device__ __forceinline__ void gload16(const void* g, void* l) {
  __builtin_amdgcn_global_load_lds(
      (const __attribute__((address_space(1))) unsigned int*)g,
      (__attribute__((address_space(3))) unsigned int*)l, 16, 0, 0);
}

// ---------------- zero scratch ----------------
__global__ void k_zero() {
  int i = blockIdx.x * 256 + threadIdx.x;          // 524288 threads
  if (i < K_CODE) g_cnt[i] = 0.0f;
  if (i < N_TOK) g_ccnt[i] = 0;
  if (i == 0) g_loss[0] = 0.0f;
  for (int j = i; j < K_CODE * D_DIM; j += 524288) g_esum[j] = 0.0f;
}

// ---------------- e_sq[k] = sum_d w[k][d]^2 (absorbed by ref rounding; order-free) ----------------
__global__ void k_esq(const float* __restrict__ wt) {
  int t = threadIdx.x;
  int code = blockIdx.x * 4 + (t >> 6);
  int l = t & 63;
  float4 v = *(const float4*)(wt + (size_t)code * D_DIM + l * 4);
  float s = v.x * v.x + v.y * v.y + v.z * v.z + v.w * v.w;
  #pragma unroll
  for (int m = 1; m < 64; m <<= 1) s += __shfl_xor(s, m, 64);
  if (l == 0) g_esq[code] = s;
}

// ---------------- codebook -> bf16, 16B-granule XOR swizzle per row ----------------
__global__ void k_split_w(const float* __restrict__ wt) {
  int tg = blockIdx.x * 256 + threadIdx.x;         // 262144 = 8192 codes * 32 granules
  int c = tg >> 5, g = tg & 31;
  const float* src = wt + (size_t)c * D_DIM + g * 8;
  float4 v0 = *(const float4*)(src);
  float4 v1 = *(const float4*)(src + 4);
  ushort8 v;
  v[0] = f2bf(v0.x); v[1] = f2bf(v0.y); v[2] = f2bf(v0.z); v[3] = f2bf(v0.w);
  v[4] = f2bf(v1.x); v[5] = f2bf(v1.y); v[6] = f2bf(v1.z); v[7] = f2bf(v1.w);
  *(ushort8*)(g_wb + (size_t)c * D_DIM + ((g ^ (c & 7)) << 3)) = v;
}

// ---------------- z_e -> flat fp32 rows + x_sq (sequential, contract-off) + bf16 swizzled ----------------
__global__ __launch_bounds__(256) void k_prep_x(const float* __restrict__ ze) {
  extern __shared__ char smem[];
  float* T = (float*)smem;                          // [64][260]
  const int tid = threadIdx.x;
  const int n0 = blockIdx.x * 64;
  const int b = n0 >> 10, hw0 = n0 & 1023;
  const float* zb = ze + (size_t)b * (D_DIM * HW) + hw0;
  #pragma unroll
  for (int p = 0; p < 16; ++p) {
    int idx = p * 256 + tid;
    int d = idx >> 4, f = idx & 15;
    float4 v = *(const float4*)(zb + (size_t)d * HW + f * 4);
    T[(f * 4 + 0) * 260 + d] = v.x;
    T[(f * 4 + 1) * 260 + d] = v.y;
    T[(f * 4 + 2) * 260 + d] = v.z;
    T[(f * 4 + 3) * 260 + d] = v.w;
  }
  __syncthreads();
  if (tid < 64) {   // x_sq: SEQUENTIAL scalar chain, square rounded before add (matches ref)
    #pragma clang fp contract(off)
    float s = 0.0f;
    const float* tr = T + tid * 260;
    for (int d = 0; d < D_DIM; ++d) { float v = tr[d]; s = s + v * v; }
    g_xsq[n0 + tid] = s;
  }
  {   // fp32 flat rows (row base 1040B = 16B-aligned)
    int r = tid >> 2, dc = (tid & 3) * 64;
    const float* tr = T + r * 260 + dc;
    float* dst = g_xf + (size_t)(n0 + r) * D_DIM + dc;
    #pragma unroll
    for (int j = 0; j < 16; ++j) *(float4*)(dst + j * 4) = *(const float4*)(tr + j * 4);
  }
  {   // bf16 rows, granule g stored at g ^ (row&7)  (row&7 == (n0+r)&7 since 64|n0)
    int r = tid >> 2, gb = (tid & 3) * 8;
    const float* tr = T + r * 260;
    ushort_t* dst = g_xb + (size_t)(n0 + r) * D_DIM;
    int swz = r & 7;
    #pragma unroll
    for (int gg = 0; gg < 8; ++gg) {
      int g = gb + gg;
      ushort8 v;
      #pragma unroll
      for (int j = 0; j < 8; ++j) v[j] = f2bf(tr[g * 8 + j]);
      *(ushort8*)(dst + ((g ^ swz) << 3)) = v;
    }
  }
}

// ---------------- bf16 MFMA GEMM, SINGLE pass: running-max + margin candidate collect ----------------
// Grid 256 = 128 row-blocks x 2 code-halves. 256 thr = 4 waves; wave w owns rows [32w,32w+32).
// LDS 128KB: A [128][256] bf16 resident + B [2][64][256] double-buffered; rows XOR-swizzled.
// Structure identical to R2's k_approx (HW-proven); only the epilogue differs (R8 HW-proven).
__global__ __launch_bounds__(256, 1) void k_approx1() {
  extern __shared__ char smem[];
  ushort_t* As = (ushort_t*)smem;                   // 64KB
  ushort_t* Bs = (ushort_t*)(smem + 65536);         // 2 x 32KB

  const int tid = threadIdx.x;
  const int lane = tid & 63, wid = tid >> 6;
  const int col = lane & 15, kg = lane >> 4;
  const int rb = blockIdx.x & 127, sp = blockIdx.x >> 7;

  {  // stage A once (linear copy of pre-swizzled rows)
    const char* s = (const char*)g_xb + (size_t)rb * 65536 + wid * 16384 + lane * 16;
    char* d = smem + wid * 16384;                   // wave-uniform base; +lane*16 implicit
    #pragma unroll
    for (int it = 0; it < 16; ++it) gload16(s + it * 1024, d + it * 1024);
  }
  const char* wsrc = (const char*)g_wb + (size_t)sp * (4096 * 512);
  {  // stage B chunk 0 -> buf 0
    const char* s = wsrc + wid * 8192 + lane * 16;
    char* d = smem + 65536 + wid * 8192;
    #pragma unroll
    for (int it = 0; it < 8; ++it) gload16(s + it * 1024, d + it * 1024);
  }

  const int rbase = rb * 128 + wid * 32;
  float rm[2][4], thr[2][4];
  #pragma unroll
  for (int m = 0; m < 2; ++m)
    #pragma unroll
    for (int r = 0; r < 4; ++r) { rm[m][r] = -1e30f; thr[m][r] = 1e30f; }

  __syncthreads();   // compiler drains vmcnt before s_barrier -> A and B0 resident

  int cur = 0;
  const int ar0 = wid * 32 + col;
  const int sw = col & 7;
  for (int ch = 0; ch < 64; ++ch) {
    if (ch < 63) {   // prefetch next chunk into other buffer
      const char* s = wsrc + (size_t)(ch + 1) * 32768 + wid * 8192 + lane * 16;
      char* d = smem + 65536 + ((cur ^ 1) << 15) + wid * 8192;
      #pragma unroll
      for (int it = 0; it < 8; ++it) gload16(s + it * 1024, d + it * 1024);
    }
    const ushort_t* Bb = Bs + (cur << 14);
    f32x4 acc[2][4];
    const f32x4 zero4 = {0.f, 0.f, 0.f, 0.f};
    #pragma unroll
    for (int m = 0; m < 2; ++m)
      #pragma unroll
      for (int n = 0; n < 4; ++n) acc[m][n] = zero4;

    #pragma unroll
    for (int ks = 0; ks < 8; ++ks) {
      const int kgr = ks * 4 + kg;
      const int ko = (kgr ^ sw) << 3;               // swizzled granule offset (8 bf16)
      short8 a0 = *(const short8*)(As + ar0 * 256 + ko);
      short8 a1 = *(const short8*)(As + (ar0 + 16) * 256 + ko);
      short8 bfr[4];
      #pragma unroll
      for (int n = 0; n < 4; ++n)
        bfr[n] = *(const short8*)(Bb + (n * 16 + col) * 256 + ko);
      #pragma unroll
      for (int n = 0; n < 4; ++n) {
        acc[0][n] = __builtin_amdgcn_mfma_f32_16x16x32_bf16(a0, bfr[n], acc[0][n], 0, 0, 0);
        acc[1][n] = __builtin_amdgcn_mfma_f32_16x16x32_bf16(a1, bfr[n], acc[1][n], 0, 0, 0);
      }
    }
    // ---- single-pass epilogue: score = 2*cross - esq; running-max + margin collect ----
    // D-frag: row = kg*4+r (+16m), col = lane&15 (R2 HW-verified mapping).
    const int c0 = sp * 4096 + ch * 64;
    float cm[2][4];
    #pragma unroll
    for (int m = 0; m < 2; ++m)
      #pragma unroll
      for (int r = 0; r < 4; ++r) cm[m][r] = -1e30f;
    #pragma unroll
    for (int n = 0; n < 4; ++n) {
      const int c = c0 + n * 16 + col;
      const float e = g_esq[c];
      #pragma unroll
      for (int m = 0; m < 2; ++m)
        #pragma unroll
        for (int r = 0; r < 4; ++r) {
          float sc = fmaf(2.0f, acc[m][n][r], -e);
          cm[m][r] = fmaxf(cm[m][r], sc);
          if (ch > 0 && sc >= thr[m][r]) {   // thr only grows -> superset of exact margin set
            int row = rbase + m * 16 + (kg << 2) + r;
            int pos = atomicAdd(&g_ccnt[row], 1);
            if (pos < RING) g_cand[row * RING + pos] = c;
          }
        }
    }
    #pragma unroll
    for (int mk = 1; mk < 16; mk <<= 1)
      #pragma unroll
      for (int m = 0; m < 2; ++m)
        #pragma unroll
        for (int r = 0; r < 4; ++r)
          cm[m][r] = fmaxf(cm[m][r], __shfl_xor(cm[m][r], mk, 64));
    #pragma unroll
    for (int m = 0; m < 2; ++m)
      #pragma unroll
      for (int r = 0; r < 4; ++r) {
        rm[m][r] = fmaxf(rm[m][r], cm[m][r]);
        thr[m][r] = rm[m][r] - MARGIN;
      }
    if (ch == 0) {   // seed chunk: push-sweep now that thr is known
      #pragma unroll
      for (int n = 0; n < 4; ++n) {
        const int c = c0 + n * 16 + col;
        const float e = g_esq[c];
        #pragma unroll
        for (int m = 0; m < 2; ++m)
          #pragma unroll
          for (int r = 0; r < 4; ++r) {
            float sc = fmaf(2.0f, acc[m][n][r], -e);
            if (sc >= thr[m][r]) {
              int row = rbase + m * 16 + (kg << 2) + r;
              int pos = atomicAdd(&g_ccnt[row], 1);
              if (pos < RING) g_cand[row * RING + pos] = c;
            }
          }
      }
    }
    __syncthreads();
    cur ^= 1;
  }
}

// ---------------- exact fp32 rescore, 4-way candidate-parallel (wave per row) ----------------
// 4 groups of 16 lanes; group q evaluates candidate i+q. 16 lanes x 16 elems per dot,
// 4-stage shfl reduce. p-rounding differs from ref GEMM by ~1e-10 << 3e-5 dist grid:
// argmin preserved (same argument HW-validated in R2/R8); exact ties -> lower code index.
__global__ __launch_bounds__(256) void k_rescore(const float* __restrict__ wt) {
  const int tid = threadIdx.x;
  const int lane = tid & 63, wid = tid >> 6;
  const int n = blockIdx.x * 4 + wid;
  const int grp = lane >> 4;        // candidate slot 0..3
  const int l15 = lane & 15;        // element group within the dot
  float4 xf[4];
  const float* xr = g_xf + (size_t)n * D_DIM + l15 * 16;
  #pragma unroll
  for (int j = 0; j < 4; ++j) xf[j] = *(const float4*)(xr + j * 4);
  const float xsq = g_xsq[n];
  const int cnt = g_ccnt[n];
  float bd = INFINITY;
  int bi = 0x7fffffff;

  auto eval4 = [&](int c, bool active) {
    float p = 0.0f;
    if (active) {
      const float* wr = wt + (size_t)c * D_DIM + l15 * 16;
      #pragma unroll
      for (int j = 0; j < 4; ++j) {
        float4 w = *(const float4*)(wr + j * 4);
        p = fmaf(xf[j].x, w.x, p);
        p = fmaf(xf[j].y, w.y, p);
        p = fmaf(xf[j].z, w.z, p);
        p = fmaf(xf[j].w, w.w, p);
      }
    }
    #pragma unroll
    for (int m = 1; m < 16; m <<= 1) p += __shfl_xor(p, m, 64);   // within 16-lane group
    if (active) {
      float d = (xsq + g_esq[c]) - 2.0f * p;   // reference rounding grid
      if (d < bd || (d == bd && c < bi)) { bd = d; bi = c; }
    }
  };

  if (cnt >= 1 && cnt <= RING) {
    for (int i = 0; i < cnt; i += 4) {
      int idx = i + grp;
      bool act = idx < cnt;
      int c = act ? g_cand[n * RING + idx] : 0;
      eval4(c, act);
    }
  } else {                                   // overflow/empty fallback: exact full scan
    for (int c0 = 0; c0 < K_CODE; c0 += 4) eval4(c0 + grp, true);
  }
  // merge the 4 groups' (bd,bi): butterfly over lane bits 4,5 with index tie-break
  #pragma unroll
  for (int m = 16; m < 64; m <<= 1) {
    float od = __shfl_xor(bd, m, 64);
    int   oi = __shfl_xor(bi, m, 64);
    if (od < bd || (od == bd && oi < bi)) { bd = od; bi = oi; }
  }
  if (lane == 0) g_idx[n] = bi;
}

// ---------------- scatter: counts + embed_sum ----------------
__global__ void k_scatter(const float* __restrict__ ze) {
  __shared__ int codes[64];
  int t = threadIdx.x;
  int n0 = blockIdx.x * 64;
  int b = n0 >> 10, hw0 = n0 & 1023;
  if (t < 64) {
    int c = g_idx[n0 + t];
    codes[t] = c;
    atomicAdd(&g_cnt[c], 1.0f);
  }
  __syncthreads();
  int f = t & 15, dd = t >> 4;
  const float* zb = ze + (size_t)b * (D_DIM * HW) + hw0;
  for (int p = 0; p < 16; ++p) {
    int d = p * 16 + dd;
    float4 v = *(const float4*)(zb + (size_t)d * HW + f * 4);
    atomicAdd(&g_esum[codes[4 * f + 0] * D_DIM + d], v.x);
    atomicAdd(&g_esum[codes[4 * f + 1] * D_DIM + d], v.y);
    atomicAdd(&g_esum[codes[4 * f + 2] * D_DIM + d], v.z);
    atomicAdd(&g_esum[codes[4 * f + 3] * D_DIM + d], v.w);
  }
}

// ---------------- EMA cluster, n, usage, inv_cs ----------------
__global__ void k_ema(const float* __restrict__ cs_in, float* __restrict__ out) {
  __shared__ float red[4];
  int t = threadIdx.x;
  float local = 0.0f;
  for (int k = t; k < K_CODE; k += 256) local += cs_in[k] * 0.99f + g_cnt[k] * 0.01f;
  #pragma unroll
  for (int m = 1; m < 64; m <<= 1) local += __shfl_xor(local, m, 64);
  if ((t & 63) == 0) red[t >> 6] = local;
  __syncthreads();
  float n = red[0] + red[1] + red[2] + red[3];
  float denom = n + 0.08192f;   // n + K*EPS
  for (int k = t; k < K_CODE; k += 256) {
    float newc = cs_in[k] * 0.99f + g_cnt[k] * 0.01f;
    out[OFF_NC + k]  = newc;
    out[OFF_USE + k] = g_cnt[k] * (1.0f / 16384.0f);
    float cs = ((newc + 1e-5f) / denom) * n;
    g_inv[k] = 1.0f / cs;
  }
}

// ---------------- new_embed_avg ----------------
__global__ void k_avg(const float* __restrict__ ea, float* __restrict__ out) {
  int i = blockIdx.x * 256 + threadIdx.x;          // 1048576 float2's
  const float2 a = *(const float2*)(ea + (size_t)i * 2);
  const float2 s = *(const float2*)(g_esum + (size_t)i * 2);
  float2 o;
  o.x = a.x * 0.99f + s.x * 0.01f;
  o.y = a.y * 0.99f + s.y * 0.01f;
  *(float2*)(out + OFF_AVG + (size_t)i * 2) = o;
}

// ---------------- gather z_q + loss ----------------
__global__ __launch_bounds__(256) void k_gather(const float* __restrict__ ze,
                                                float* __restrict__ out) {
  __shared__ float W[32 * 260];
  __shared__ int codes[64];
  __shared__ float red[4];
  const float* avg = out + OFF_AVG;
  int t = threadIdx.x;
  int n0 = blockIdx.x * 64;
  int b = n0 >> 10, hw0 = n0 & 1023;
  if (t < 64) codes[t] = g_idx[n0 + t];
  float l = 0.0f;
  const float* zb = ze + (size_t)b * (D_DIM * HW);
  float* qb = out + OFF_ZQ + (size_t)b * (D_DIM * HW);
  for (int pass = 0; pass < 2; ++pass) {
    __syncthreads();
    {
      int rr0 = t >> 6;
      int f = t & 63;
      for (int q = 0; q < 8; ++q) {
        int rr = q * 4 + rr0;
        int c = codes[pass * 32 + rr];
        float iv = g_inv[c];
        float2 w0 = *(const float2*)(avg + (size_t)c * D_DIM + f * 4);
        float2 w1 = *(const float2*)(avg + (size_t)c * D_DIM + f * 4 + 2);
        float* wp = &W[rr * 260 + f * 4];
        wp[0] = w0.x * iv; wp[1] = w0.y * iv; wp[2] = w1.x * iv; wp[3] = w1.y * iv;
      }
    }
    __syncthreads();
    int f = t & 7, dd = t >> 3;
    int hwp = hw0 + pass * 32;
    for (int p = 0; p < 8; ++p) {
      int d = p * 32 + dd;
      float4 zev = *(const float4*)(zb + (size_t)d * HW + hwp + f * 4);
      float4 o;
      o.x = W[(4 * f + 0) * 260 + d];
      o.y = W[(4 * f + 1) * 260 + d];
      o.z = W[(4 * f + 2) * 260 + d];
      o.w = W[(4 * f + 3) * 260 + d];
      *(float4*)(qb + (size_t)d * HW + hwp + f * 4) = o;
      float dx = zev.x - o.x, dy = zev.y - o.y, dz = zev.z - o.z, dw = zev.w - o.w;
      l += dx * dx; l += dy * dy; l += dz * dz; l += dw * dw;
    }
  }
  #pragma unroll
  for (int m = 1; m < 64; m <<= 1) l += __shfl_xor(l, m, 64);
  if ((t & 63) == 0) red[t >> 6] = l;
  __syncthreads();
  if (t == 0) atomicAdd(g_loss, red[0] + red[1] + red[2] + red[3]);
}

// ---------------- final scalars ----------------
__global__ void k_final(float* __restrict__ out) {
  if (threadIdx.x == 0) {
    float mse = g_loss[0] * (1.0f / 4194304.0f);
    out[OFF_CL]  = 0.25f * mse;
    out[OFF_CBL] = mse;
  }
}

extern "C" void kernel_launch(void* const* d_in, const int* in_sizes, int n_in,
                              void* d_out, int out_size, void* d_ws, size_t ws_size,
                              hipStream_t stream) {
  const float* ze    = (const float*)d_in[0];
  const float* wt    = (const float*)d_in[1];
  const float* cs_in = (const float*)d_in[2];
  const float* ea_in = (const float*)d_in[3];
  float* out = (float*)d_out;
  (void)in_sizes; (void)n_in; (void)out_size; (void)d_ws; (void)ws_size;

  // Dynamic-LDS opt-ins (idempotent; not stream ops)
  (void)hipFuncSetAttribute((const void*)k_prep_x,
                            hipFuncAttributeMaxDynamicSharedMemorySize, 66560);
  (void)hipFuncSetAttribute((const void*)k_approx1,
                            hipFuncAttributeMaxDynamicSharedMemorySize, 131072);

  k_zero<<<2048, 256, 0, stream>>>();
  k_esq<<<K_CODE / 4, 256, 0, stream>>>(wt);
  k_split_w<<<1024, 256, 0, stream>>>(wt);
  k_prep_x<<<N_TOK / 64, 256, 66560, stream>>>(ze);
  k_approx1<<<256, 256, 131072, stream>>>();
  k_rescore<<<N_TOK / 4, 256, 0, stream>>>(wt);
  k_scatter<<<N_TOK / 64, 256, 0, stream>>>(ze);
  k_ema<<<1, 256, 0, stream>>>(cs_in, out);
  k_avg<<<4096, 256, 0, stream>>>(ea_in, out);
  k_gather<<<N_TOK / 64, 256, 0, stream>>>(ze, out);
  k_final<<<1, 64, 0, stream>>>(out);
}

// Round 10
// 463.405 us; speedup vs baseline: 9.1205x; 1.3664x over previous
//
#include <hip/hip_runtime.h>
#include <cstdint>
#include <cstddef>

// Problem constants
#define N_TOK   16384      // 16*32*32 tokens
#define K_CODE  8192
#define D_DIM   256
#define HW      1024       // 32*32
#define MARGIN  8e-4f      // >= 2*bf16 err bound + dist-grid/tie slack, 2x safety (R2-proven)
#define RING    512
#define CAP     990        // per-wave LDS push-list entries

// d_out layout (floats): z_q, commit, codebook, usage, new_cluster, new_embed_avg
#define OFF_ZQ   0
#define OFF_CL   4194304
#define OFF_CBL  4194305
#define OFF_USE  4194306
#define OFF_NC   4202498
#define OFF_AVG  4210690

typedef unsigned short ushort_t;
typedef __attribute__((ext_vector_type(8))) short short8;
typedef __attribute__((ext_vector_type(8))) unsigned short ushort8;
typedef __attribute__((ext_vector_type(4))) float f32x4;

// Device-global scratch
__device__ float g_esq[K_CODE];
__device__ float g_xsq[N_TOK];
__device__ __attribute__((aligned(16))) float    g_xf[N_TOK * D_DIM];   // flat fp32 [n][d]
__device__ __attribute__((aligned(16))) ushort_t g_xb[N_TOK * D_DIM];   // bf16, row-swizzled
__device__ __attribute__((aligned(16))) ushort_t g_wb[K_CODE * D_DIM];  // bf16, row-swizzled
__device__ int   g_ccnt[N_TOK];
__device__ int   g_cand[N_TOK * RING];
__device__ int   g_idx[N_TOK];
__device__ float g_cnt[K_CODE];
__device__ __attribute__((aligned(16))) float g_esum[K_CODE * D_DIM];
__device__ float g_inv[K_CODE];
__device__ float g_loss[1];

__device__ __forceinline__ ushort_t f2bf(float f) {
  unsigned u = __builtin_bit_cast(unsigned, f);
  return (ushort_t)((u + 0x7FFFu + ((u >> 16) & 1u)) >> 16);   // RNE, no NaN in data
}

__device__ __forceinline__ void gload16(const void* g, void* l) {
  __builtin_amdgcn_global_load_lds(
      (const __attribute__((address_space(1))) unsigned int*)g,
      (__attribute__((address_space(3))) unsigned int*)l, 16, 0, 0);
}

// ---------------- zero scratch ----------------
__global__ void k_zero() {
  int i = blockIdx.x * 256 + threadIdx.x;          // 524288 threads
  if (i < K_CODE) g_cnt[i] = 0.0f;
  if (i < N_TOK) g_ccnt[i] = 0;
  if (i == 0) g_loss[0] = 0.0f;
  for (int j = i; j < K_CODE * D_DIM; j += 524288) g_esum[j] = 0.0f;
}

// ---------------- e_sq[k] = sum_d w[k][d]^2 (absorbed by ref rounding; order-free) ----------------
__global__ void k_esq(const float* __restrict__ wt) {
  int t = threadIdx.x;
  int code = blockIdx.x * 4 + (t >> 6);
  int l = t & 63;
  float4 v = *(const float4*)(wt + (size_t)code * D_DIM + l * 4);
  float s = v.x * v.x + v.y * v.y + v.z * v.z + v.w * v.w;
  #pragma unroll
  for (int m = 1; m < 64; m <<= 1) s += __shfl_xor(s, m, 64);
  if (l == 0) g_esq[code] = s;
}

// ---------------- codebook -> bf16, 16B-granule XOR swizzle per row ----------------
__global__ void k_split_w(const float* __restrict__ wt) {
  int tg = blockIdx.x * 256 + threadIdx.x;         // 262144 = 8192 codes * 32 granules
  int c = tg >> 5, g = tg & 31;
  const float* src = wt + (size_t)c * D_DIM + g * 8;
  float4 v0 = *(const float4*)(src);
  float4 v1 = *(const float4*)(src + 4);
  ushort8 v;
  v[0] = f2bf(v0.x); v[1] = f2bf(v0.y); v[2] = f2bf(v0.z); v[3] = f2bf(v0.w);
  v[4] = f2bf(v1.x); v[5] = f2bf(v1.y); v[6] = f2bf(v1.z); v[7] = f2bf(v1.w);
  *(ushort8*)(g_wb + (size_t)c * D_DIM + ((g ^ (c & 7)) << 3)) = v;
}

// ---------------- z_e -> flat fp32 rows + x_sq (sequential, contract-off) + bf16 swizzled ----------------
__global__ __launch_bounds__(256) void k_prep_x(const float* __restrict__ ze) {
  extern __shared__ char smem[];
  float* T = (float*)smem;                          // [64][260]
  const int tid = threadIdx.x;
  const int n0 = blockIdx.x * 64;
  const int b = n0 >> 10, hw0 = n0 & 1023;
  const float* zb = ze + (size_t)b * (D_DIM * HW) + hw0;
  #pragma unroll
  for (int p = 0; p < 16; ++p) {
    int idx = p * 256 + tid;
    int d = idx >> 4, f = idx & 15;
    float4 v = *(const float4*)(zb + (size_t)d * HW + f * 4);
    T[(f * 4 + 0) * 260 + d] = v.x;
    T[(f * 4 + 1) * 260 + d] = v.y;
    T[(f * 4 + 2) * 260 + d] = v.z;
    T[(f * 4 + 3) * 260 + d] = v.w;
  }
  __syncthreads();
  if (tid < 64) {   // x_sq: SEQUENTIAL scalar chain, square rounded before add (matches ref)
    #pragma clang fp contract(off)
    float s = 0.0f;
    const float* tr = T + tid * 260;
    for (int d = 0; d < D_DIM; ++d) { float v = tr[d]; s = s + v * v; }
    g_xsq[n0 + tid] = s;
  }
  {   // fp32 flat rows (row base 1040B = 16B-aligned)
    int r = tid >> 2, dc = (tid & 3) * 64;
    const float* tr = T + r * 260 + dc;
    float* dst = g_xf + (size_t)(n0 + r) * D_DIM + dc;
    #pragma unroll
    for (int j = 0; j < 16; ++j) *(float4*)(dst + j * 4) = *(const float4*)(tr + j * 4);
  }
  {   // bf16 rows, granule g stored at g ^ (row&7)  (row&7 == (n0+r)&7 since 64|n0)
    int r = tid >> 2, gb = (tid & 3) * 8;
    const float* tr = T + r * 260;
    ushort_t* dst = g_xb + (size_t)(n0 + r) * D_DIM;
    int swz = r & 7;
    #pragma unroll
    for (int gg = 0; gg < 8; ++gg) {
      int g = gb + gg;
      ushort8 v;
      #pragma unroll
      for (int j = 0; j < 8; ++j) v[j] = f2bf(tr[g * 8 + j]);
      *(ushort8*)(dst + ((g ^ swz) << 3)) = v;
    }
  }
}

// ---------------- bf16 MFMA GEMM, single pass, 2 blocks/CU, LDS-buffered collect ----------------
// Grid 512 = 256 row-blocks x 2 code-halves. 256 thr = 4 waves; wave owns ONE 16-row group.
// LDS (79.5KB -> 2 blocks/CU): A [64][256] 32KB + B dbuf 2x[32][256] 32KB + push lists 15.5KB.
// esq read direct from global (L2-hot), prefetched per chunk. Collect: per-wave LDS list
// (ds_add_rtn) + end flush; overflow -> direct global (correct, rare).
__global__ __launch_bounds__(256, 1) void k_approx1() {
  extern __shared__ char smem[];
  ushort_t* As = (ushort_t*)smem;                           // 32KB
  ushort_t* Bs = (ushort_t*)(smem + 32768);                 // 2 x 16KB
  int* lcnt = (int*)(smem + 65536);                         // 4 counters
  // per-wave push lists: base 65552, stride 3960B (CAP=990)

  const int tid = threadIdx.x;
  const int lane = tid & 63, wid = tid >> 6;
  const int col = lane & 15, kg = lane >> 4;
  const int rb = blockIdx.x & 255, sp = blockIdx.x >> 8;
  const int sw = col & 7;
  int* lbuf = (int*)(smem + 65552 + wid * 3960);

  if (tid < 4) lcnt[tid] = 0;

  {  // stage A once (64 rows x 512B = 32KB; linear copy of pre-swizzled rows)
    const char* s = (const char*)g_xb + (size_t)rb * 32768 + wid * 1024 + lane * 16;
    char* d = smem + wid * 1024;                            // wave-uniform base
    #pragma unroll
    for (int it = 0; it < 8; ++it) gload16(s + it * 4096, d + it * 4096);
  }
  const char* wsrc = (const char*)g_wb + (size_t)sp * (4096 * 512);
  {  // stage B chunk 0 -> buf 0 (32 codes x 512B = 16KB)
    const char* s = wsrc + wid * 1024 + lane * 16;
    char* d = smem + 32768 + wid * 1024;
    #pragma unroll
    for (int it = 0; it < 4; ++it) gload16(s + it * 4096, d + it * 4096);
  }

  const int rowbase = rb * 64 + wid * 16 + (kg << 2);       // + r = global row
  float rm[4], thr[4];
  #pragma unroll
  for (int r = 0; r < 4; ++r) { rm[r] = -1e30f; thr[r] = 1e30f; }

  __syncthreads();   // A + B0 resident (compiler drains vmcnt before s_barrier)

  const int ar0 = (wid * 16 + col) * 256;
  #pragma unroll 1
  for (int ch = 0; ch < 128; ++ch) {
    const int cur = ch & 1;
    const int c0 = sp * 4096 + ch * 32;
    // prefetch esq for this chunk's two col-tiles (L2-hot; hidden under MFMA)
    float e0 = g_esq[c0 + col];
    float e1 = g_esq[c0 + 16 + col];
    if (ch < 127) {   // prefetch next chunk into other buffer
      const char* s = wsrc + (size_t)(ch + 1) * 16384 + wid * 1024 + lane * 16;
      char* d = smem + 32768 + ((cur ^ 1) << 14) + wid * 1024;
      #pragma unroll
      for (int it = 0; it < 4; ++it) gload16(s + it * 4096, d + it * 4096);
    }
    const ushort_t* Bb = Bs + (cur << 13);
    f32x4 acc0 = {0.f, 0.f, 0.f, 0.f};
    f32x4 acc1 = {0.f, 0.f, 0.f, 0.f};

    #pragma unroll
    for (int ks = 0; ks < 8; ++ks) {
      const int ko = ((ks * 4 + kg) ^ sw) << 3;             // swizzled granule offset
      short8 a  = *(const short8*)(As + ar0 + ko);
      short8 b0 = *(const short8*)(Bb + (col +  0) * 256 + ko);
      short8 b1 = *(const short8*)(Bb + (col + 16) * 256 + ko);
      acc0 = __builtin_amdgcn_mfma_f32_16x16x32_bf16(a, b0, acc0, 0, 0, 0);
      acc1 = __builtin_amdgcn_mfma_f32_16x16x32_bf16(a, b1, acc1, 0, 0, 0);
    }

    // ---- epilogue: score = 2*cross - esq; running-max + LDS-buffered margin collect ----
    float cm[4];
    #pragma unroll
    for (int r = 0; r < 4; ++r) cm[r] = -1e30f;
    #pragma unroll
    for (int n = 0; n < 2; ++n) {
      const int c = c0 + n * 16 + col;
      const float e = n ? e1 : e0;
      const f32x4& a4 = n ? acc1 : acc0;
      #pragma unroll
      for (int r = 0; r < 4; ++r) {
        float sc = fmaf(2.0f, a4[r], -e);
        cm[r] = fmaxf(cm[r], sc);
        if (ch > 0 && sc >= thr[r]) {   // thr only grows -> superset of exact margin set
          int row = rowbase + r;
          int pos = atomicAdd(&lcnt[wid], 1);
          if (pos < CAP) lbuf[pos] = (row << 13) | c;
          else { int gp = atomicAdd(&g_ccnt[row], 1);
                 if (gp < RING) g_cand[row * RING + gp] = c; }
        }
      }
    }
    #pragma unroll
    for (int mk = 1; mk < 16; mk <<= 1)
      #pragma unroll
      for (int r = 0; r < 4; ++r)
        cm[r] = fmaxf(cm[r], __shfl_xor(cm[r], mk, 64));
    #pragma unroll
    for (int r = 0; r < 4; ++r) {
      rm[r] = fmaxf(rm[r], cm[r]);
      thr[r] = rm[r] - MARGIN;
    }
    if (ch == 0) {   // seed chunk: push-sweep now that thr is known
      #pragma unroll
      for (int n = 0; n < 2; ++n) {
        const int c = c0 + n * 16 + col;
        const float e = n ? e1 : e0;
        const f32x4& a4 = n ? acc1 : acc0;
        #pragma unroll
        for (int r = 0; r < 4; ++r) {
          float sc = fmaf(2.0f, a4[r], -e);
          if (sc >= thr[r]) {
            int row = rowbase + r;
            int pos = atomicAdd(&lcnt[wid], 1);
            if (pos < CAP) lbuf[pos] = (row << 13) | c;
            else { int gp = atomicAdd(&g_ccnt[row], 1);
                   if (gp < RING) g_cand[row * RING + gp] = c; }
          }
        }
      }
    }
    __syncthreads();   // next buf staged + all waves done reading buf[cur]
  }

  // ---- flush per-wave LDS list to global (batched, 64-lane parallel) ----
  __syncthreads();
  int k = lcnt[wid];
  if (k > CAP) k = CAP;
  for (int i = lane; i < k; i += 64) {
    int e = lbuf[i];
    int row = e >> 13, c = e & 8191;
    int pos = atomicAdd(&g_ccnt[row], 1);
    if (pos < RING) g_cand[row * RING + pos] = c;
  }
}

// ---------------- exact fp32 rescore, 4-way candidate-parallel (wave per row) ----------------
__global__ __launch_bounds__(256) void k_rescore(const float* __restrict__ wt) {
  const int tid = threadIdx.x;
  const int lane = tid & 63, wid = tid >> 6;
  const int n = blockIdx.x * 4 + wid;
  const int grp = lane >> 4;        // candidate slot 0..3
  const int l15 = lane & 15;        // element group within the dot
  float4 xf[4];
  const float* xr = g_xf + (size_t)n * D_DIM + l15 * 16;
  #pragma unroll
  for (int j = 0; j < 4; ++j) xf[j] = *(const float4*)(xr + j * 4);
  const float xsq = g_xsq[n];
  const int cnt = g_ccnt[n];
  float bd = INFINITY;
  int bi = 0x7fffffff;

  auto eval4 = [&](int c, bool active) {
    float p = 0.0f;
    if (active) {
      const float* wr = wt + (size_t)c * D_DIM + l15 * 16;
      #pragma unroll
      for (int j = 0; j < 4; ++j) {
        float4 w = *(const float4*)(wr + j * 4);
        p = fmaf(xf[j].x, w.x, p);
        p = fmaf(xf[j].y, w.y, p);
        p = fmaf(xf[j].z, w.z, p);
        p = fmaf(xf[j].w, w.w, p);
      }
    }
    #pragma unroll
    for (int m = 1; m < 16; m <<= 1) p += __shfl_xor(p, m, 64);   // within 16-lane group
    if (active) {
      float d = (xsq + g_esq[c]) - 2.0f * p;   // reference rounding grid
      if (d < bd || (d == bd && c < bi)) { bd = d; bi = c; }
    }
  };

  if (cnt >= 1 && cnt <= RING) {
    for (int i = 0; i < cnt; i += 4) {
      int idx = i + grp;
      bool act = idx < cnt;
      int c = act ? g_cand[n * RING + idx] : 0;
      eval4(c, act);
    }
  } else {                                   // overflow/empty fallback: exact full scan
    for (int c0 = 0; c0 < K_CODE; c0 += 4) eval4(c0 + grp, true);
  }
  // merge the 4 groups' (bd,bi): butterfly over lane bits 4,5 with index tie-break
  #pragma unroll
  for (int m = 16; m < 64; m <<= 1) {
    float od = __shfl_xor(bd, m, 64);
    int   oi = __shfl_xor(bi, m, 64);
    if (od < bd || (od == bd && oi < bi)) { bd = od; bi = oi; }
  }
  if (lane == 0) g_idx[n] = bi;
}

// ---------------- scatter: counts + embed_sum ----------------
__global__ void k_scatter(const float* __restrict__ ze) {
  __shared__ int codes[64];
  int t = threadIdx.x;
  int n0 = blockIdx.x * 64;
  int b = n0 >> 10, hw0 = n0 & 1023;
  if (t < 64) {
    int c = g_idx[n0 + t];
    codes[t] = c;
    atomicAdd(&g_cnt[c], 1.0f);
  }
  __syncthreads();
  int f = t & 15, dd = t >> 4;
  const float* zb = ze + (size_t)b * (D_DIM * HW) + hw0;
  for (int p = 0; p < 16; ++p) {
    int d = p * 16 + dd;
    float4 v = *(const float4*)(zb + (size_t)d * HW + f * 4);
    atomicAdd(&g_esum[codes[4 * f + 0] * D_DIM + d], v.x);
    atomicAdd(&g_esum[codes[4 * f + 1] * D_DIM + d], v.y);
    atomicAdd(&g_esum[codes[4 * f + 2] * D_DIM + d], v.z);
    atomicAdd(&g_esum[codes[4 * f + 3] * D_DIM + d], v.w);
  }
}

// ---------------- EMA cluster, n, usage, inv_cs ----------------
__global__ void k_ema(const float* __restrict__ cs_in, float* __restrict__ out) {
  __shared__ float red[4];
  int t = threadIdx.x;
  float local = 0.0f;
  for (int k = t; k < K_CODE; k += 256) local += cs_in[k] * 0.99f + g_cnt[k] * 0.01f;
  #pragma unroll
  for (int m = 1; m < 64; m <<= 1) local += __shfl_xor(local, m, 64);
  if ((t & 63) == 0) red[t >> 6] = local;
  __syncthreads();
  float n = red[0] + red[1] + red[2] + red[3];
  float denom = n + 0.08192f;   // n + K*EPS
  for (int k = t; k < K_CODE; k += 256) {
    float newc = cs_in[k] * 0.99f + g_cnt[k] * 0.01f;
    out[OFF_NC + k]  = newc;
    out[OFF_USE + k] = g_cnt[k] * (1.0f / 16384.0f);
    float cs = ((newc + 1e-5f) / denom) * n;
    g_inv[k] = 1.0f / cs;
  }
}

// ---------------- new_embed_avg ----------------
__global__ void k_avg(const float* __restrict__ ea, float* __restrict__ out) {
  int i = blockIdx.x * 256 + threadIdx.x;          // 1048576 float2's
  const float2 a = *(const float2*)(ea + (size_t)i * 2);
  const float2 s = *(const float2*)(g_esum + (size_t)i * 2);
  float2 o;
  o.x = a.x * 0.99f + s.x * 0.01f;
  o.y = a.y * 0.99f + s.y * 0.01f;
  *(float2*)(out + OFF_AVG + (size_t)i * 2) = o;
}

// ---------------- gather z_q + loss ----------------
__global__ __launch_bounds__(256) void k_gather(const float* __restrict__ ze,
                                                float* __restrict__ out) {
  __shared__ float W[32 * 260];
  __shared__ int codes[64];
  __shared__ float red[4];
  const float* avg = out + OFF_AVG;
  int t = threadIdx.x;
  int n0 = blockIdx.x * 64;
  int b = n0 >> 10, hw0 = n0 & 1023;
  if (t < 64) codes[t] = g_idx[n0 + t];
  float l = 0.0f;
  const float* zb = ze + (size_t)b * (D_DIM * HW);
  float* qb = out + OFF_ZQ + (size_t)b * (D_DIM * HW);
  for (int pass = 0; pass < 2; ++pass) {
    __syncthreads();
    {
      int rr0 = t >> 6;
      int f = t & 63;
      for (int q = 0; q < 8; ++q) {
        int rr = q * 4 + rr0;
        int c = codes[pass * 32 + rr];
        float iv = g_inv[c];
        float2 w0 = *(const float2*)(avg + (size_t)c * D_DIM + f * 4);
        float2 w1 = *(const float2*)(avg + (size_t)c * D_DIM + f * 4 + 2);
        float* wp = &W[rr * 260 + f * 4];
        wp[0] = w0.x * iv; wp[1] = w0.y * iv; wp[2] = w1.x * iv; wp[3] = w1.y * iv;
      }
    }
    __syncthreads();
    int f = t & 7, dd = t >> 3;
    int hwp = hw0 + pass * 32;
    for (int p = 0; p < 8; ++p) {
      int d = p * 32 + dd;
      float4 zev = *(const float4*)(zb + (size_t)d * HW + hwp + f * 4);
      float4 o;
      o.x = W[(4 * f + 0) * 260 + d];
      o.y = W[(4 * f + 1) * 260 + d];
      o.z = W[(4 * f + 2) * 260 + d];
      o.w = W[(4 * f + 3) * 260 + d];
      *(float4*)(qb + (size_t)d * HW + hwp + f * 4) = o;
      float dx = zev.x - o.x, dy = zev.y - o.y, dz = zev.z - o.z, dw = zev.w - o.w;
      l += dx * dx; l += dy * dy; l += dz * dz; l += dw * dw;
    }
  }
  #pragma unroll
  for (int m = 1; m < 64; m <<= 1) l += __shfl_xor(l, m, 64);
  if ((t & 63) == 0) red[t >> 6] = l;
  __syncthreads();
  if (t == 0) atomicAdd(g_loss, red[0] + red[1] + red[2] + red[3]);
}

// ---------------- final scalars ----------------
__global__ void k_final(float* __restrict__ out) {
  if (threadIdx.x == 0) {
    float mse = g_loss[0] * (1.0f / 4194304.0f);
    out[OFF_CL]  = 0.25f * mse;
    out[OFF_CBL] = mse;
  }
}

extern "C" void kernel_launch(void* const* d_in, const int* in_sizes, int n_in,
                              void* d_out, int out_size, void* d_ws, size_t ws_size,
                              hipStream_t stream) {
  const float* ze    = (const float*)d_in[0];
  const float* wt    = (const float*)d_in[1];
  const float* cs_in = (const float*)d_in[2];
  const float* ea_in = (const float*)d_in[3];
  float* out = (float*)d_out;
  (void)in_sizes; (void)n_in; (void)out_size; (void)d_ws; (void)ws_size;

  // Dynamic-LDS opt-ins (idempotent; not stream ops)
  (void)hipFuncSetAttribute((const void*)k_prep_x,
                            hipFuncAttributeMaxDynamicSharedMemorySize, 66560);
  (void)hipFuncSetAttribute((const void*)k_approx1,
                            hipFuncAttributeMaxDynamicSharedMemorySize, 81408);

  k_zero<<<2048, 256, 0, stream>>>();
  k_esq<<<K_CODE / 4, 256, 0, stream>>>(wt);
  k_split_w<<<1024, 256, 0, stream>>>(wt);
  k_prep_x<<<N_TOK / 64, 256, 66560, stream>>>(ze);
  k_approx1<<<512, 256, 81408, stream>>>();
  k_rescore<<<N_TOK / 4, 256, 0, stream>>>(wt);
  k_scatter<<<N_TOK / 64, 256, 0, stream>>>(ze);
  k_ema<<<1, 256, 0, stream>>>(cs_in, out);
  k_avg<<<4096, 256, 0, stream>>>(ea_in, out);
  k_gather<<<N_TOK / 64, 256, 0, stream>>>(ze, out);
  k_final<<<1, 64, 0, stream>>>(out);
}

// Round 11
// 455.844 us; speedup vs baseline: 9.2718x; 1.0166x over previous
//
#include <hip/hip_runtime.h>
#include <cstdint>
#include <cstddef>

// Problem constants
#define N_TOK   16384      // 16*32*32 tokens
#define K_CODE  8192
#define D_DIM   256
#define HW      1024       // 32*32
#define MARGIN  8e-4f      // >= 2*bf16 err bound + dist-grid/tie slack, 2x safety (R2-proven)
#define RING    512
#define CAP     990        // per-wave LDS push-list entries

// d_out layout (floats): z_q, commit, codebook, usage, new_cluster, new_embed_avg
#define OFF_ZQ   0
#define OFF_CL   4194304
#define OFF_CBL  4194305
#define OFF_USE  4194306
#define OFF_NC   4202498
#define OFF_AVG  4210690

typedef unsigned short ushort_t;
typedef __attribute__((ext_vector_type(8))) short short8;
typedef __attribute__((ext_vector_type(8))) unsigned short ushort8;
typedef __attribute__((ext_vector_type(4))) float f32x4;

// Device-global scratch
__device__ float g_esq[K_CODE];
__device__ float g_xsq[N_TOK];
__device__ __attribute__((aligned(16))) float    g_xf[N_TOK * D_DIM];   // flat fp32 [n][d]
__device__ __attribute__((aligned(16))) ushort_t g_xb[N_TOK * D_DIM];   // bf16, row-swizzled
__device__ __attribute__((aligned(16))) ushort_t g_wb[K_CODE * D_DIM];  // bf16, row-swizzled
__device__ int   g_ccnt[N_TOK];
__device__ int   g_cand[N_TOK * RING];
__device__ int   g_idx[N_TOK];
__device__ float g_cnt[K_CODE];
__device__ __attribute__((aligned(16))) float g_esum[K_CODE * D_DIM];
__device__ float g_inv[K_CODE];
__device__ float g_loss[1];

__device__ __forceinline__ ushort_t f2bf(float f) {
  unsigned u = __builtin_bit_cast(unsigned, f);
  return (ushort_t)((u + 0x7FFFu + ((u >> 16) & 1u)) >> 16);   // RNE, no NaN in data
}

__device__ __forceinline__ void gload16(const void* g, void* l) {
  __builtin_amdgcn_global_load_lds(
      (const __attribute__((address_space(1))) unsigned int*)g,
      (__attribute__((address_space(3))) unsigned int*)l, 16, 0, 0);
}

// ---------------- zero scratch ----------------
__global__ void k_zero() {
  int i = blockIdx.x * 256 + threadIdx.x;          // 524288 threads
  if (i < K_CODE) g_cnt[i] = 0.0f;
  if (i < N_TOK) g_ccnt[i] = 0;
  if (i == 0) g_loss[0] = 0.0f;
  for (int j = i; j < K_CODE * D_DIM; j += 524288) g_esum[j] = 0.0f;
}

// ---------------- e_sq[k] = sum_d w[k][d]^2 (absorbed by ref rounding; order-free) ----------------
__global__ void k_esq(const float* __restrict__ wt) {
  int t = threadIdx.x;
  int code = blockIdx.x * 4 + (t >> 6);
  int l = t & 63;
  float4 v = *(const float4*)(wt + (size_t)code * D_DIM + l * 4);
  float s = v.x * v.x + v.y * v.y + v.z * v.z + v.w * v.w;
  #pragma unroll
  for (int m = 1; m < 64; m <<= 1) s += __shfl_xor(s, m, 64);
  if (l == 0) g_esq[code] = s;
}

// ---------------- codebook -> bf16, 16B-granule XOR swizzle per row ----------------
__global__ void k_split_w(const float* __restrict__ wt) {
  int tg = blockIdx.x * 256 + threadIdx.x;         // 262144 = 8192 codes * 32 granules
  int c = tg >> 5, g = tg & 31;
  const float* src = wt + (size_t)c * D_DIM + g * 8;
  float4 v0 = *(const float4*)(src);
  float4 v1 = *(const float4*)(src + 4);
  ushort8 v;
  v[0] = f2bf(v0.x); v[1] = f2bf(v0.y); v[2] = f2bf(v0.z); v[3] = f2bf(v0.w);
  v[4] = f2bf(v1.x); v[5] = f2bf(v1.y); v[6] = f2bf(v1.z); v[7] = f2bf(v1.w);
  *(ushort8*)(g_wb + (size_t)c * D_DIM + ((g ^ (c & 7)) << 3)) = v;
}

// ---------------- z_e -> flat fp32 rows + x_sq (sequential, contract-off) + bf16 swizzled ----------------
__global__ __launch_bounds__(256) void k_prep_x(const float* __restrict__ ze) {
  extern __shared__ char smem[];
  float* T = (float*)smem;                          // [64][260]
  const int tid = threadIdx.x;
  const int n0 = blockIdx.x * 64;
  const int b = n0 >> 10, hw0 = n0 & 1023;
  const float* zb = ze + (size_t)b * (D_DIM * HW) + hw0;
  #pragma unroll
  for (int p = 0; p < 16; ++p) {
    int idx = p * 256 + tid;
    int d = idx >> 4, f = idx & 15;
    float4 v = *(const float4*)(zb + (size_t)d * HW + f * 4);
    T[(f * 4 + 0) * 260 + d] = v.x;
    T[(f * 4 + 1) * 260 + d] = v.y;
    T[(f * 4 + 2) * 260 + d] = v.z;
    T[(f * 4 + 3) * 260 + d] = v.w;
  }
  __syncthreads();
  if (tid < 64) {   // x_sq: SEQUENTIAL scalar chain, square rounded before add (matches ref)
    #pragma clang fp contract(off)
    float s = 0.0f;
    const float* tr = T + tid * 260;
    for (int d = 0; d < D_DIM; ++d) { float v = tr[d]; s = s + v * v; }
    g_xsq[n0 + tid] = s;
  }
  {   // fp32 flat rows (row base 1040B = 16B-aligned)
    int r = tid >> 2, dc = (tid & 3) * 64;
    const float* tr = T + r * 260 + dc;
    float* dst = g_xf + (size_t)(n0 + r) * D_DIM + dc;
    #pragma unroll
    for (int j = 0; j < 16; ++j) *(float4*)(dst + j * 4) = *(const float4*)(tr + j * 4);
  }
  {   // bf16 rows, granule g stored at g ^ (row&7)  (row&7 == (n0+r)&7 since 64|n0)
    int r = tid >> 2, gb = (tid & 3) * 8;
    const float* tr = T + r * 260;
    ushort_t* dst = g_xb + (size_t)(n0 + r) * D_DIM;
    int swz = r & 7;
    #pragma unroll
    for (int gg = 0; gg < 8; ++gg) {
      int g = gb + gg;
      ushort8 v;
      #pragma unroll
      for (int j = 0; j < 8; ++j) v[j] = f2bf(tr[g * 8 + j]);
      *(ushort8*)(dst + ((g ^ swz) << 3)) = v;
    }
  }
}

// ---------------- bf16 MFMA GEMM: A in VGPRs, B-only LDS, LDS-buffered collect ----------------
// Grid 512 = 128 rowblocks(128 rows) x 4 code-quarters(2048 codes). 256 thr = 4 waves;
// wave owns 32 rows (16 A-frags = 64 VGPR, loaded per-lane from R10-proven g_xb layout).
// LDS 47.5KB (2 blocks/CU): B dbuf 2x16KB + push lists. 64 chunks x 32 codes.
// 16 ds_read_b128 per chunk/wave for 32 MFMA (0.5 reads/MFMA; was 1.5 in R10).
__global__ __launch_bounds__(256, 1) void k_approx1() {
  extern __shared__ char smem[];
  ushort_t* Bs = (ushort_t*)smem;                           // 2 x 16KB
  int* lcnt = (int*)(smem + 32768);                         // 4 counters
  const int tid = threadIdx.x;
  const int lane = tid & 63, wid = tid >> 6;
  const int col = lane & 15, kg = lane >> 4;
  const int rb = blockIdx.x & 127, sp = blockIdx.x >> 7;
  const int sw = col & 7;
  const int rbase = rb * 128 + wid * 32;
  int* lbuf = (int*)(smem + 32784 + wid * 3960);            // CAP=990 ints per wave

  if (tid < 4) lcnt[tid] = 0;

  // A fragments from g_xb (row-swizzled; same address formula as the R2-proven LDS read).
  // Frag (ks,m): lane holds row rbase+m*16+col, elements k = ks*32 + kg*8 .. +7.
  short8 af[16];
  #pragma unroll
  for (int ks = 0; ks < 8; ++ks)
    #pragma unroll
    for (int m = 0; m < 2; ++m) {
      int row = rbase + m * 16 + col;                       // row&7 == col&7 == sw
      af[ks * 2 + m] = *(const short8*)(g_xb + (size_t)row * 256 + (((ks * 4 + kg) ^ sw) << 3));
    }

  const char* wsrc = (const char*)g_wb + (size_t)sp * (2048 * 512);
  {  // stage B chunk 0 -> buf 0 (32 codes x 512B = 16KB)
    const char* s = wsrc + wid * 1024 + lane * 16;
    char* d = smem + wid * 1024;
    #pragma unroll
    for (int it = 0; it < 4; ++it) gload16(s + it * 4096, d + it * 4096);
  }

  float rm[2][4], thr[2][4];
  #pragma unroll
  for (int m = 0; m < 2; ++m)
    #pragma unroll
    for (int r = 0; r < 4; ++r) { rm[m][r] = -1e30f; thr[m][r] = 1e30f; }

  __syncthreads();   // B0 resident (compiler drains vmcnt before s_barrier)

  #pragma unroll 1
  for (int ch = 0; ch < 64; ++ch) {
    const int cur = ch & 1;
    const int c0 = sp * 2048 + ch * 32;
    // esq for this chunk's two col-tiles (L2-hot; hidden under MFMA)
    float e0 = g_esq[c0 + col];
    float e1 = g_esq[c0 + 16 + col];
    if (ch < 63) {   // prefetch next chunk into other buffer
      const char* s = wsrc + (size_t)(ch + 1) * 16384 + wid * 1024 + lane * 16;
      char* d = smem + ((cur ^ 1) << 14) + wid * 1024;
      #pragma unroll
      for (int it = 0; it < 4; ++it) gload16(s + it * 4096, d + it * 4096);
    }
    const ushort_t* Bb = Bs + (cur << 13);
    f32x4 acc[2][2];
    const f32x4 zero4 = {0.f, 0.f, 0.f, 0.f};
    #pragma unroll
    for (int m = 0; m < 2; ++m)
      #pragma unroll
      for (int n = 0; n < 2; ++n) acc[m][n] = zero4;

    #pragma unroll
    for (int ks = 0; ks < 8; ++ks) {
      const int ko = ((ks * 4 + kg) ^ sw) << 3;             // swizzled granule offset
      short8 b0 = *(const short8*)(Bb + (col +  0) * 256 + ko);
      short8 b1 = *(const short8*)(Bb + (col + 16) * 256 + ko);
      acc[0][0] = __builtin_amdgcn_mfma_f32_16x16x32_bf16(af[ks*2+0], b0, acc[0][0], 0, 0, 0);
      acc[1][0] = __builtin_amdgcn_mfma_f32_16x16x32_bf16(af[ks*2+1], b0, acc[1][0], 0, 0, 0);
      acc[0][1] = __builtin_amdgcn_mfma_f32_16x16x32_bf16(af[ks*2+0], b1, acc[0][1], 0, 0, 0);
      acc[1][1] = __builtin_amdgcn_mfma_f32_16x16x32_bf16(af[ks*2+1], b1, acc[1][1], 0, 0, 0);
    }

    // ---- epilogue: score = 2*cross - esq; running-max + LDS-buffered margin collect ----
    float cm[2][4], sv[2][2][4];
    #pragma unroll
    for (int m = 0; m < 2; ++m)
      #pragma unroll
      for (int r = 0; r < 4; ++r) cm[m][r] = -1e30f;
    #pragma unroll
    for (int n = 0; n < 2; ++n) {
      const float e = n ? e1 : e0;
      #pragma unroll
      for (int m = 0; m < 2; ++m)
        #pragma unroll
        for (int r = 0; r < 4; ++r) {
          float sc = fmaf(2.0f, acc[m][n][r], -e);
          sv[m][n][r] = sc;
          cm[m][r] = fmaxf(cm[m][r], sc);
        }
    }
    if (ch > 0) {   // push with pre-update thr (thr only grows -> superset of exact set)
      #pragma unroll
      for (int n = 0; n < 2; ++n) {
        const int c = c0 + n * 16 + col;
        #pragma unroll
        for (int m = 0; m < 2; ++m)
          #pragma unroll
          for (int r = 0; r < 4; ++r)
            if (sv[m][n][r] >= thr[m][r]) {
              int row = rbase + m * 16 + (kg << 2) + r;
              int pos = atomicAdd(&lcnt[wid], 1);
              if (pos < CAP) lbuf[pos] = (row << 13) | c;
              else { int gp = atomicAdd(&g_ccnt[row], 1);
                     if (gp < RING) g_cand[row * RING + gp] = c; }
            }
      }
    }
    #pragma unroll
    for (int mk = 1; mk < 16; mk <<= 1)
      #pragma unroll
      for (int m = 0; m < 2; ++m)
        #pragma unroll
        for (int r = 0; r < 4; ++r)
          cm[m][r] = fmaxf(cm[m][r], __shfl_xor(cm[m][r], mk, 64));
    #pragma unroll
    for (int m = 0; m < 2; ++m)
      #pragma unroll
      for (int r = 0; r < 4; ++r) {
        rm[m][r] = fmaxf(rm[m][r], cm[m][r]);
        thr[m][r] = rm[m][r] - MARGIN;
      }
    if (ch == 0) {   // seed chunk: push-sweep now that thr is known
      #pragma unroll
      for (int n = 0; n < 2; ++n) {
        const int c = c0 + n * 16 + col;
        #pragma unroll
        for (int m = 0; m < 2; ++m)
          #pragma unroll
          for (int r = 0; r < 4; ++r)
            if (sv[m][n][r] >= thr[m][r]) {
              int row = rbase + m * 16 + (kg << 2) + r;
              int pos = atomicAdd(&lcnt[wid], 1);
              if (pos < CAP) lbuf[pos] = (row << 13) | c;
              else { int gp = atomicAdd(&g_ccnt[row], 1);
                     if (gp < RING) g_cand[row * RING + gp] = c; }
            }
      }
    }
    __syncthreads();   // next buf staged + all waves done reading buf[cur]
  }

  // ---- flush per-wave LDS list to global (batched, 64-lane parallel) ----
  __syncthreads();
  int k = lcnt[wid];
  if (k > CAP) k = CAP;
  for (int i = lane; i < k; i += 64) {
    int e = lbuf[i];
    int row = e >> 13, c = e & 8191;
    int pos = atomicAdd(&g_ccnt[row], 1);
    if (pos < RING) g_cand[row * RING + pos] = c;
  }
}

// ---------------- exact fp32 rescore, 4-way candidate-parallel (wave per row) ----------------
__global__ __launch_bounds__(256) void k_rescore(const float* __restrict__ wt) {
  const int tid = threadIdx.x;
  const int lane = tid & 63, wid = tid >> 6;
  const int n = blockIdx.x * 4 + wid;
  const int grp = lane >> 4;        // candidate slot 0..3
  const int l15 = lane & 15;        // element group within the dot
  float4 xf[4];
  const float* xr = g_xf + (size_t)n * D_DIM + l15 * 16;
  #pragma unroll
  for (int j = 0; j < 4; ++j) xf[j] = *(const float4*)(xr + j * 4);
  const float xsq = g_xsq[n];
  const int cnt = g_ccnt[n];
  float bd = INFINITY;
  int bi = 0x7fffffff;

  auto eval4 = [&](int c, bool active) {
    float p = 0.0f;
    if (active) {
      const float* wr = wt + (size_t)c * D_DIM + l15 * 16;
      #pragma unroll
      for (int j = 0; j < 4; ++j) {
        float4 w = *(const float4*)(wr + j * 4);
        p = fmaf(xf[j].x, w.x, p);
        p = fmaf(xf[j].y, w.y, p);
        p = fmaf(xf[j].z, w.z, p);
        p = fmaf(xf[j].w, w.w, p);
      }
    }
    #pragma unroll
    for (int m = 1; m < 16; m <<= 1) p += __shfl_xor(p, m, 64);   // within 16-lane group
    if (active) {
      float d = (xsq + g_esq[c]) - 2.0f * p;   // reference rounding grid
      if (d < bd || (d == bd && c < bi)) { bd = d; bi = c; }
    }
  };

  if (cnt >= 1 && cnt <= RING) {
    for (int i = 0; i < cnt; i += 4) {
      int idx = i + grp;
      bool act = idx < cnt;
      int c = act ? g_cand[n * RING + idx] : 0;
      eval4(c, act);
    }
  } else {                                   // overflow/empty fallback: exact full scan
    for (int c0 = 0; c0 < K_CODE; c0 += 4) eval4(c0 + grp, true);
  }
  // merge the 4 groups' (bd,bi): butterfly over lane bits 4,5 with index tie-break
  #pragma unroll
  for (int m = 16; m < 64; m <<= 1) {
    float od = __shfl_xor(bd, m, 64);
    int   oi = __shfl_xor(bi, m, 64);
    if (od < bd || (od == bd && oi < bi)) { bd = od; bi = oi; }
  }
  if (lane == 0) g_idx[n] = bi;
}

// ---------------- scatter: counts + embed_sum ----------------
__global__ void k_scatter(const float* __restrict__ ze) {
  __shared__ int codes[64];
  int t = threadIdx.x;
  int n0 = blockIdx.x * 64;
  int b = n0 >> 10, hw0 = n0 & 1023;
  if (t < 64) {
    int c = g_idx[n0 + t];
    codes[t] = c;
    atomicAdd(&g_cnt[c], 1.0f);
  }
  __syncthreads();
  int f = t & 15, dd = t >> 4;
  const float* zb = ze + (size_t)b * (D_DIM * HW) + hw0;
  for (int p = 0; p < 16; ++p) {
    int d = p * 16 + dd;
    float4 v = *(const float4*)(zb + (size_t)d * HW + f * 4);
    atomicAdd(&g_esum[codes[4 * f + 0] * D_DIM + d], v.x);
    atomicAdd(&g_esum[codes[4 * f + 1] * D_DIM + d], v.y);
    atomicAdd(&g_esum[codes[4 * f + 2] * D_DIM + d], v.z);
    atomicAdd(&g_esum[codes[4 * f + 3] * D_DIM + d], v.w);
  }
}

// ---------------- EMA cluster, n, usage, inv_cs ----------------
__global__ void k_ema(const float* __restrict__ cs_in, float* __restrict__ out) {
  __shared__ float red[4];
  int t = threadIdx.x;
  float local = 0.0f;
  for (int k = t; k < K_CODE; k += 256) local += cs_in[k] * 0.99f + g_cnt[k] * 0.01f;
  #pragma unroll
  for (int m = 1; m < 64; m <<= 1) local += __shfl_xor(local, m, 64);
  if ((t & 63) == 0) red[t >> 6] = local;
  __syncthreads();
  float n = red[0] + red[1] + red[2] + red[3];
  float denom = n + 0.08192f;   // n + K*EPS
  for (int k = t; k < K_CODE; k += 256) {
    float newc = cs_in[k] * 0.99f + g_cnt[k] * 0.01f;
    out[OFF_NC + k]  = newc;
    out[OFF_USE + k] = g_cnt[k] * (1.0f / 16384.0f);
    float cs = ((newc + 1e-5f) / denom) * n;
    g_inv[k] = 1.0f / cs;
  }
}

// ---------------- new_embed_avg ----------------
__global__ void k_avg(const float* __restrict__ ea, float* __restrict__ out) {
  int i = blockIdx.x * 256 + threadIdx.x;          // 1048576 float2's
  const float2 a = *(const float2*)(ea + (size_t)i * 2);
  const float2 s = *(const float2*)(g_esum + (size_t)i * 2);
  float2 o;
  o.x = a.x * 0.99f + s.x * 0.01f;
  o.y = a.y * 0.99f + s.y * 0.01f;
  *(float2*)(out + OFF_AVG + (size_t)i * 2) = o;
}

// ---------------- gather z_q + loss ----------------
__global__ __launch_bounds__(256) void k_gather(const float* __restrict__ ze,
                                                float* __restrict__ out) {
  __shared__ float W[32 * 260];
  __shared__ int codes[64];
  __shared__ float red[4];
  const float* avg = out + OFF_AVG;
  int t = threadIdx.x;
  int n0 = blockIdx.x * 64;
  int b = n0 >> 10, hw0 = n0 & 1023;
  if (t < 64) codes[t] = g_idx[n0 + t];
  float l = 0.0f;
  const float* zb = ze + (size_t)b * (D_DIM * HW);
  float* qb = out + OFF_ZQ + (size_t)b * (D_DIM * HW);
  for (int pass = 0; pass < 2; ++pass) {
    __syncthreads();
    {
      int rr0 = t >> 6;
      int f = t & 63;
      for (int q = 0; q < 8; ++q) {
        int rr = q * 4 + rr0;
        int c = codes[pass * 32 + rr];
        float iv = g_inv[c];
        float2 w0 = *(const float2*)(avg + (size_t)c * D_DIM + f * 4);
        float2 w1 = *(const float2*)(avg + (size_t)c * D_DIM + f * 4 + 2);
        float* wp = &W[rr * 260 + f * 4];
        wp[0] = w0.x * iv; wp[1] = w0.y * iv; wp[2] = w1.x * iv; wp[3] = w1.y * iv;
      }
    }
    __syncthreads();
    int f = t & 7, dd = t >> 3;
    int hwp = hw0 + pass * 32;
    for (int p = 0; p < 8; ++p) {
      int d = p * 32 + dd;
      float4 zev = *(const float4*)(zb + (size_t)d * HW + hwp + f * 4);
      float4 o;
      o.x = W[(4 * f + 0) * 260 + d];
      o.y = W[(4 * f + 1) * 260 + d];
      o.z = W[(4 * f + 2) * 260 + d];
      o.w = W[(4 * f + 3) * 260 + d];
      *(float4*)(qb + (size_t)d * HW + hwp + f * 4) = o;
      float dx = zev.x - o.x, dy = zev.y - o.y, dz = zev.z - o.z, dw = zev.w - o.w;
      l += dx * dx; l += dy * dy; l += dz * dz; l += dw * dw;
    }
  }
  #pragma unroll
  for (int m = 1; m < 64; m <<= 1) l += __shfl_xor(l, m, 64);
  if ((t & 63) == 0) red[t >> 6] = l;
  __syncthreads();
  if (t == 0) atomicAdd(g_loss, red[0] + red[1] + red[2] + red[3]);
}

// ---------------- final scalars ----------------
__global__ void k_final(float* __restrict__ out) {
  if (threadIdx.x == 0) {
    float mse = g_loss[0] * (1.0f / 4194304.0f);
    out[OFF_CL]  = 0.25f * mse;
    out[OFF_CBL] = mse;
  }
}

extern "C" void kernel_launch(void* const* d_in, const int* in_sizes, int n_in,
                              void* d_out, int out_size, void* d_ws, size_t ws_size,
                              hipStream_t stream) {
  const float* ze    = (const float*)d_in[0];
  const float* wt    = (const float*)d_in[1];
  const float* cs_in = (const float*)d_in[2];
  const float* ea_in = (const float*)d_in[3];
  float* out = (float*)d_out;
  (void)in_sizes; (void)n_in; (void)out_size; (void)d_ws; (void)ws_size;

  // Dynamic-LDS opt-ins (idempotent; not stream ops)
  (void)hipFuncSetAttribute((const void*)k_prep_x,
                            hipFuncAttributeMaxDynamicSharedMemorySize, 66560);
  (void)hipFuncSetAttribute((const void*)k_approx1,
                            hipFuncAttributeMaxDynamicSharedMemorySize, 48640);

  k_zero<<<2048, 256, 0, stream>>>();
  k_esq<<<K_CODE / 4, 256, 0, stream>>>(wt);
  k_split_w<<<1024, 256, 0, stream>>>(wt);
  k_prep_x<<<N_TOK / 64, 256, 66560, stream>>>(ze);
  k_approx1<<<512, 256, 48640, stream>>>();
  k_rescore<<<N_TOK / 4, 256, 0, stream>>>(wt);
  k_scatter<<<N_TOK / 64, 256, 0, stream>>>(ze);
  k_ema<<<1, 256, 0, stream>>>(cs_in, out);
  k_avg<<<4096, 256, 0, stream>>>(ea_in, out);
  k_gather<<<N_TOK / 64, 256, 0, stream>>>(ze, out);
  k_final<<<1, 64, 0, stream>>>(out);
}